// Round 5
// baseline (15549.699 us; speedup 1.0000x reference)
//
#include <hip/hip_runtime.h>

#define Bn 64
#define Tn 2048
#define In 128
#define Hn 256
#define RS 512  // row stride in f16 elements for pre/out rows (1024 B)

typedef _Float16 h2 __attribute__((ext_vector_type(2)));
typedef _Float16 f16x8 __attribute__((ext_vector_type(8)));
typedef float f32x4 __attribute__((ext_vector_type(4)));

__device__ __forceinline__ float fast_sigmoid(float x) {
    return 1.0f / (1.0f + __expf(-x));
}
__device__ __forceinline__ float fast_tanh(float x) {
    return 2.0f / (1.0f + __expf(-2.0f * x)) - 1.0f;
}
__device__ __forceinline__ h2 bc2(float f) {
    return __builtin_bit_cast(h2, f);
}

#if __has_builtin(__builtin_amdgcn_fdot2)
__device__ __forceinline__ float dot2(h2 a, h2 b, float c) {
    return __builtin_amdgcn_fdot2(a, b, c, false);
}
#else
__device__ __forceinline__ float dot2(h2 a, h2 b, float c) {
    return c + (float)a.x * (float)b.x + (float)a.y * (float)b.y;
}
#endif

// ---------------------------------------------------------------------------
// K1: pre0[m][512] (f16, in d_out) = X[m][0:128] @ [Wih0 | Wax0] + [bh0 | ba0]
// ---------------------------------------------------------------------------
__global__ void gemm_x_kernel(const float* __restrict__ X,
                              const float* __restrict__ Wih0, const float* __restrict__ bh0,
                              const float* __restrict__ Wax0, const float* __restrict__ ba0,
                              _Float16* __restrict__ pre)
{
    __shared__ __align__(16) float Xs[64 * In];  // 32 KB
    const int m0 = blockIdx.x * 64;
    const int s  = blockIdx.y;
    const float* __restrict__ W    = s ? Wax0 : Wih0;
    const float* __restrict__ bias = s ? ba0  : bh0;

    {
        const float4* __restrict__ src = reinterpret_cast<const float4*>(X + (size_t)m0 * In);
        float4* __restrict__ dst = reinterpret_cast<float4*>(Xs);
        #pragma unroll
        for (int i = 0; i < 8; ++i) dst[threadIdx.x + 256 * i] = src[threadIdx.x + 256 * i];
    }
    __syncthreads();

    const int c  = threadIdx.x & 63;
    const int rg = threadIdx.x >> 6;
    const int mr = rg * 16;

    float acc[16][4];
    #pragma unroll
    for (int u = 0; u < 4; ++u) {
        const float bv = bias[c + 64 * u];
        #pragma unroll
        for (int r = 0; r < 16; ++r) acc[r][u] = bv;
    }

    const float4* __restrict__ Xs4 = reinterpret_cast<const float4*>(Xs);
    #pragma unroll 4
    for (int kc = 0; kc < 32; ++kc) {
        float wv[4][4];
        #pragma unroll
        for (int kk = 0; kk < 4; ++kk)
            #pragma unroll
            for (int u = 0; u < 4; ++u)
                wv[kk][u] = W[(size_t)(4 * kc + kk) * Hn + c + 64 * u];
        #pragma unroll
        for (int r = 0; r < 16; ++r) {
            const float4 xv = Xs4[(mr + r) * 32 + kc];
            #pragma unroll
            for (int u = 0; u < 4; ++u)
                acc[r][u] += xv.x * wv[0][u] + xv.y * wv[1][u] + xv.z * wv[2][u] + xv.w * wv[3][u];
        }
    }

    #pragma unroll
    for (int r = 0; r < 16; ++r)
        #pragma unroll
        for (int u = 0; u < 4; ++u)
            pre[(size_t)(m0 + mr + r) * RS + s * Hn + c + 64 * u] = (_Float16)acc[r][u];
}

// ---------------------------------------------------------------------------
// K3: pre1 (in-place over pre rows) = h0seq(f16) @ [Wih1 | Wax1] + bias
// ---------------------------------------------------------------------------
__global__ void gemm_h_kernel(_Float16* __restrict__ pre,
                              const float* __restrict__ Wih1, const float* __restrict__ bh1,
                              const float* __restrict__ Wax1, const float* __restrict__ ba1)
{
    __shared__ __align__(16) _Float16 Hs[32 * Hn];  // 16 KB
    const int m0 = blockIdx.x * 32;

    {
        float4* __restrict__ dst = reinterpret_cast<float4*>(Hs);
        #pragma unroll
        for (int q = 0; q < 4; ++q) {
            const int id  = threadIdx.x + 256 * q;
            const int row = id >> 5;
            const int off = id & 31;
            const float4* __restrict__ src =
                reinterpret_cast<const float4*>(pre + (size_t)(m0 + row) * RS);
            dst[row * 32 + off] = src[off];
        }
    }
    __syncthreads();

    const int c  = threadIdx.x & 63;
    const int rg = threadIdx.x >> 6;
    const int mr = rg * 8;

    const float* Wp[8];
    float acc[8][8];
    #pragma unroll
    for (int u = 0; u < 8; ++u) {
        const int colu = c + 64 * u;
        const float bv = (colu < Hn) ? bh1[colu] : ba1[colu - Hn];
        Wp[u] = (colu < Hn) ? (Wih1 + colu) : (Wax1 + (colu - Hn));
        #pragma unroll
        for (int r = 0; r < 8; ++r) acc[r][u] = bv;
    }

    const float2* __restrict__ Hs2 = reinterpret_cast<const float2*>(Hs);
    #pragma unroll 2
    for (int kc = 0; kc < 64; ++kc) {
        float wv[4][8];
        #pragma unroll
        for (int kk = 0; kk < 4; ++kk)
            #pragma unroll
            for (int u = 0; u < 8; ++u)
                wv[kk][u] = Wp[u][(size_t)(4 * kc + kk) * Hn];
        #pragma unroll
        for (int r = 0; r < 8; ++r) {
            const float2 q = Hs2[(mr + r) * 64 + kc];
            const h2 p0 = bc2(q.x), p1 = bc2(q.y);
            const float f0 = (float)p0.x, f1 = (float)p0.y, f2 = (float)p1.x, f3 = (float)p1.y;
            #pragma unroll
            for (int u = 0; u < 8; ++u)
                acc[r][u] += f0 * wv[0][u] + f1 * wv[1][u] + f2 * wv[2][u] + f3 * wv[3][u];
        }
    }

    #pragma unroll
    for (int r = 0; r < 8; ++r)
        #pragma unroll
        for (int u = 0; u < 8; ++u)
            pre[(size_t)(m0 + mr + r) * RS + c + 64 * u] = (_Float16)acc[r][u];
}

// ---------------------------------------------------------------------------
// Scan v5: minimal diff from the PASSING R2 kernel. Only the inner product
// changed: MFMA + lane-select replaced by 256 v_dot2_f32_f16 per thread
// (thread tid owns column tid of both matvecs, weights as 2x128 h2 VGPRs).
// Everything else is R2 verbatim: 256 threads / 4 waves, double-buffered
// hbuf, ONE __syncthreads per step, chunked register prefetch (pUc/pAc),
// chunk-end batched global stores (hst).
// ---------------------------------------------------------------------------
__global__ __launch_bounds__(256, 1)
void scan_dot2_kernel(_Float16* __restrict__ pre,
                      const float* __restrict__ WU, const float* __restrict__ WA,
                      float* __restrict__ outf, float* __restrict__ hfin, int writeF32)
{
    __shared__ __align__(16) _Float16 hbuf[2][Hn];   // 1 KB

    const int b   = blockIdx.x;
    const int col = threadIdx.x;     // output column 0..255

    // ---- weights: column `col` of WU / WA, packed h2 per k-pair ----
    h2 bu[128], ba[128];
    #pragma unroll
    for (int k2 = 0; k2 < 128; ++k2) {
        h2 u, a;
        u.x = (_Float16)WU[(size_t)(2 * k2)     * Hn + col];
        u.y = (_Float16)WU[(size_t)(2 * k2 + 1) * Hn + col];
        a.x = (_Float16)WA[(size_t)(2 * k2)     * Hn + col];
        a.y = (_Float16)WA[(size_t)(2 * k2 + 1) * Hn + col];
        bu[k2] = u;
        ba[k2] = a;
    }

    _Float16* __restrict__ rowbase = pre + (size_t)b * Tn * RS;
    float hprev = 0.0f;

    // prologue: h0 = 0; prefetch pre rows 0..7 into registers
    hbuf[0][col] = (_Float16)0.0f;
    float pUc[8], pAc[8];
    #pragma unroll
    for (int k = 0; k < 8; ++k) {
        pUc[k] = (float)rowbase[(size_t)k * RS + col];
        pAc[k] = (float)rowbase[(size_t)k * RS + Hn + col];
    }
    __syncthreads();

    for (int t0 = 0; t0 < Tn; t0 += 8) {
        // ---- batched prefetch of rows t0+8 .. t0+15 into registers ----
        float pUn[8], pAn[8];
        #pragma unroll
        for (int k = 0; k < 8; ++k) {
            int tn = t0 + 8 + k;
            if (tn > Tn - 1) tn = Tn - 1;
            pUn[k] = (float)rowbase[(size_t)tn * RS + col];
            pAn[k] = (float)rowbase[(size_t)tn * RS + Hn + col];
        }

        float hst[8];   // h values of this chunk (store batch)

        #pragma unroll
        for (int ph = 0; ph < 8; ++ph) {
            const int t = t0 + ph;

            const f16x8* __restrict__ hb =
                reinterpret_cast<const f16x8*>(&hbuf[t & 1][0]);

            float accU[4] = {0.0f, 0.0f, 0.0f, 0.0f};
            float accA[4] = {0.0f, 0.0f, 0.0f, 0.0f};

            // 32 broadcast b128 reads; 4 h2-pairs each; 8 indep dot chains
            #pragma unroll
            for (int r = 0; r < 32; ++r) {
                const f16x8 v = hb[r];                       // h[8r .. 8r+7]
                const h2 p0 = __builtin_shufflevector(v, v, 0, 1);
                const h2 p1 = __builtin_shufflevector(v, v, 2, 3);
                const h2 p2 = __builtin_shufflevector(v, v, 4, 5);
                const h2 p3 = __builtin_shufflevector(v, v, 6, 7);
                accU[0] = dot2(p0, bu[4 * r + 0], accU[0]);
                accU[1] = dot2(p1, bu[4 * r + 1], accU[1]);
                accU[2] = dot2(p2, bu[4 * r + 2], accU[2]);
                accU[3] = dot2(p3, bu[4 * r + 3], accU[3]);
                accA[0] = dot2(p0, ba[4 * r + 0], accA[0]);
                accA[1] = dot2(p1, ba[4 * r + 1], accA[1]);
                accA[2] = dot2(p2, ba[4 * r + 2], accA[2]);
                accA[3] = dot2(p3, ba[4 * r + 3], accA[3]);
            }

            const float yU = (accU[0] + accU[1]) + (accU[2] + accU[3]);
            const float yA = (accA[0] + accA[1]) + (accA[2] + accA[3]);

            // ---- in-register activation (R2 form: pre added here) ----
            const float cand  = fast_tanh(yU + pUc[ph]);
            const float alpha = fast_sigmoid(yA + pAc[ph]);
            const float hn = alpha * cand + (1.0f - alpha) * hprev;
            hprev = hn;
            hst[ph] = hn;
            hbuf[(t + 1) & 1][col] = (_Float16)hn;

            __syncthreads();   // h_new visible; h reads of this step done
        }

        // ---- chunk flush: batched global stores + rotate prefetch regs ----
        if (writeF32) {
            #pragma unroll
            for (int k = 0; k < 8; ++k)
                outf[((size_t)b * Tn + (t0 + k)) * Hn + col] = hst[k];
        } else {
            #pragma unroll
            for (int k = 0; k < 8; ++k)
                rowbase[(size_t)(t0 + k) * RS + col] = (_Float16)hst[k];
        }
        #pragma unroll
        for (int k = 0; k < 8; ++k) { pUc[k] = pUn[k]; pAc[k] = pAn[k]; }
    }

    hfin[b * Hn + col] = hprev;
}

extern "C" void kernel_launch(void* const* d_in, const int* in_sizes, int n_in,
                              void* d_out, int out_size, void* d_ws, size_t ws_size,
                              hipStream_t stream) {
    const float* X    = (const float*)d_in[0];
    const float* Wih0 = (const float*)d_in[1];
    const float* Whh0 = (const float*)d_in[2];
    const float* bh0  = (const float*)d_in[3];
    const float* Wax0 = (const float*)d_in[4];
    const float* Wah0 = (const float*)d_in[5];
    const float* ba0  = (const float*)d_in[6];
    const float* Wih1 = (const float*)d_in[7];
    const float* Whh1 = (const float*)d_in[8];
    const float* bh1  = (const float*)d_in[9];
    const float* Wax1 = (const float*)d_in[10];
    const float* Wah1 = (const float*)d_in[11];
    const float* ba1  = (const float*)d_in[12];

    float* outf = (float*)d_out;
    float* hfin = outf + (size_t)Bn * Tn * Hn;
    _Float16* pre = (_Float16*)d_out;

    gemm_x_kernel<<<dim3((Bn * Tn) / 64, 2), 256, 0, stream>>>(X, Wih0, bh0, Wax0, ba0, pre);
    scan_dot2_kernel<<<dim3(Bn), 256, 0, stream>>>(pre, Whh0, Wah0, outf, hfin, 0);
    gemm_h_kernel<<<dim3((Bn * Tn) / 32), 256, 0, stream>>>(pre, Wih1, bh1, Wax1, ba1);
    scan_dot2_kernel<<<dim3(Bn), 256, 0, stream>>>(pre, Whh1, Wah1, outf, hfin + Bn * Hn, 1);
}

// Round 6
// 4384.681 us; speedup vs baseline: 3.5464x; 3.5464x over previous
//
#include <hip/hip_runtime.h>

#define Bn 64
#define Tn 2048
#define In 128
#define Hn 256
#define RS 512  // row stride in f16 elements for pre/out rows (1024 B)

typedef _Float16 h2 __attribute__((ext_vector_type(2)));
typedef _Float16 f16x8 __attribute__((ext_vector_type(8)));
typedef float f32x4 __attribute__((ext_vector_type(4)));

__device__ __forceinline__ float fast_sigmoid(float x) {
    return 1.0f / (1.0f + __expf(-x));
}
__device__ __forceinline__ float fast_tanh(float x) {
    return 2.0f / (1.0f + __expf(-2.0f * x)) - 1.0f;
}
__device__ __forceinline__ h2 bc2(float f) {
    return __builtin_bit_cast(h2, f);
}

#if __has_builtin(__builtin_amdgcn_fdot2)
__device__ __forceinline__ float dot2(h2 a, h2 b, float c) {
    return __builtin_amdgcn_fdot2(a, b, c, false);
}
#else
__device__ __forceinline__ float dot2(h2 a, h2 b, float c) {
    return c + (float)a.x * (float)b.x + (float)a.y * (float)b.y;
}
#endif

// ---------------------------------------------------------------------------
// K1: pre0[m][512] (f16, in d_out) = X[m][0:128] @ [Wih0 | Wax0] + [bh0 | ba0]
// ---------------------------------------------------------------------------
__global__ void gemm_x_kernel(const float* __restrict__ X,
                              const float* __restrict__ Wih0, const float* __restrict__ bh0,
                              const float* __restrict__ Wax0, const float* __restrict__ ba0,
                              _Float16* __restrict__ pre)
{
    __shared__ __align__(16) float Xs[64 * In];  // 32 KB
    const int m0 = blockIdx.x * 64;
    const int s  = blockIdx.y;
    const float* __restrict__ W    = s ? Wax0 : Wih0;
    const float* __restrict__ bias = s ? ba0  : bh0;

    {
        const float4* __restrict__ src = reinterpret_cast<const float4*>(X + (size_t)m0 * In);
        float4* __restrict__ dst = reinterpret_cast<float4*>(Xs);
        #pragma unroll
        for (int i = 0; i < 8; ++i) dst[threadIdx.x + 256 * i] = src[threadIdx.x + 256 * i];
    }
    __syncthreads();

    const int c  = threadIdx.x & 63;
    const int rg = threadIdx.x >> 6;
    const int mr = rg * 16;

    float acc[16][4];
    #pragma unroll
    for (int u = 0; u < 4; ++u) {
        const float bv = bias[c + 64 * u];
        #pragma unroll
        for (int r = 0; r < 16; ++r) acc[r][u] = bv;
    }

    const float4* __restrict__ Xs4 = reinterpret_cast<const float4*>(Xs);
    #pragma unroll 4
    for (int kc = 0; kc < 32; ++kc) {
        float wv[4][4];
        #pragma unroll
        for (int kk = 0; kk < 4; ++kk)
            #pragma unroll
            for (int u = 0; u < 4; ++u)
                wv[kk][u] = W[(size_t)(4 * kc + kk) * Hn + c + 64 * u];
        #pragma unroll
        for (int r = 0; r < 16; ++r) {
            const float4 xv = Xs4[(mr + r) * 32 + kc];
            #pragma unroll
            for (int u = 0; u < 4; ++u)
                acc[r][u] += xv.x * wv[0][u] + xv.y * wv[1][u] + xv.z * wv[2][u] + xv.w * wv[3][u];
        }
    }

    #pragma unroll
    for (int r = 0; r < 16; ++r)
        #pragma unroll
        for (int u = 0; u < 4; ++u)
            pre[(size_t)(m0 + mr + r) * RS + s * Hn + c + 64 * u] = (_Float16)acc[r][u];
}

// ---------------------------------------------------------------------------
// K3: pre1 (in-place over pre rows) = h0seq(f16) @ [Wih1 | Wax1] + bias
// ---------------------------------------------------------------------------
__global__ void gemm_h_kernel(_Float16* __restrict__ pre,
                              const float* __restrict__ Wih1, const float* __restrict__ bh1,
                              const float* __restrict__ Wax1, const float* __restrict__ ba1)
{
    __shared__ __align__(16) _Float16 Hs[32 * Hn];  // 16 KB
    const int m0 = blockIdx.x * 32;

    {
        float4* __restrict__ dst = reinterpret_cast<float4*>(Hs);
        #pragma unroll
        for (int q = 0; q < 4; ++q) {
            const int id  = threadIdx.x + 256 * q;
            const int row = id >> 5;
            const int off = id & 31;
            const float4* __restrict__ src =
                reinterpret_cast<const float4*>(pre + (size_t)(m0 + row) * RS);
            dst[row * 32 + off] = src[off];
        }
    }
    __syncthreads();

    const int c  = threadIdx.x & 63;
    const int rg = threadIdx.x >> 6;
    const int mr = rg * 8;

    const float* Wp[8];
    float acc[8][8];
    #pragma unroll
    for (int u = 0; u < 8; ++u) {
        const int colu = c + 64 * u;
        const float bv = (colu < Hn) ? bh1[colu] : ba1[colu - Hn];
        Wp[u] = (colu < Hn) ? (Wih1 + colu) : (Wax1 + (colu - Hn));
        #pragma unroll
        for (int r = 0; r < 8; ++r) acc[r][u] = bv;
    }

    const float2* __restrict__ Hs2 = reinterpret_cast<const float2*>(Hs);
    #pragma unroll 2
    for (int kc = 0; kc < 64; ++kc) {
        float wv[4][8];
        #pragma unroll
        for (int kk = 0; kk < 4; ++kk)
            #pragma unroll
            for (int u = 0; u < 8; ++u)
                wv[kk][u] = Wp[u][(size_t)(4 * kc + kk) * Hn];
        #pragma unroll
        for (int r = 0; r < 8; ++r) {
            const float2 q = Hs2[(mr + r) * 64 + kc];
            const h2 p0 = bc2(q.x), p1 = bc2(q.y);
            const float f0 = (float)p0.x, f1 = (float)p0.y, f2 = (float)p1.x, f3 = (float)p1.y;
            #pragma unroll
            for (int u = 0; u < 8; ++u)
                acc[r][u] += f0 * wv[0][u] + f1 * wv[1][u] + f2 * wv[2][u] + f3 * wv[3][u];
        }
    }

    #pragma unroll
    for (int r = 0; r < 8; ++r)
        #pragma unroll
        for (int u = 0; u < 8; ++u)
            pre[(size_t)(m0 + mr + r) * RS + c + 64 * u] = (_Float16)acc[r][u];
}

// ---------------------------------------------------------------------------
// Scan v6: dot2 datapath (proven correct in R5), spill-free via matvec
// split. 64 blocks x 512 threads (8 waves, 2/SIMD). Thread (mv, col):
// waves 0-3 are mv=0 (U/tanh path), waves 4-7 are mv=1 (A/sigmoid path);
// each thread holds ONE weight column as 128 h2 VGPRs (~190 total regs,
// fits under the 256 arch cap -> no scratch).
//
// Step: both groups compute y = W[:,col]. h + pre (128 fdot2, 4-acc
// rotation, h via 32 broadcast b128 LDS reads); mv=1 computes
// alpha = sigmoid(yA) PRE-barrier and publishes it; mv=0 computes
// cand = tanh(yU) pre-barrier; after barrier 1 mv=0 does only
// hn = hprev + alpha*(cand - hprev), writes hbuf; barrier 2 propagates h.
// Chunked register prefetch + chunk-end batched stores (R2-proven).
// ---------------------------------------------------------------------------
__global__ __launch_bounds__(512, 2)
void scan_dot2_kernel(_Float16* __restrict__ pre,
                      const float* __restrict__ WU, const float* __restrict__ WA,
                      float* __restrict__ outf, float* __restrict__ hfin, int writeF32)
{
    __shared__ __align__(16) _Float16 hbuf[2][Hn];   // 1 KB
    __shared__ __align__(16) float    abuf[Hn];      // 1 KB (published alpha)

    const int b   = blockIdx.x;
    const int tid = threadIdx.x;
    const int col = tid & 255;       // output column
    const int mv  = tid >> 8;        // 0 = U (tanh), 1 = A (sigmoid); wave-uniform

    // ---- weights: column `col` of this thread's matrix, h2-packed ----
    const float* __restrict__ Wm = mv ? WA : WU;
    h2 bw[128];
    #pragma unroll
    for (int k2 = 0; k2 < 128; ++k2) {
        h2 u;
        u.x = (_Float16)Wm[(size_t)(2 * k2)     * Hn + col];
        u.y = (_Float16)Wm[(size_t)(2 * k2 + 1) * Hn + col];
        bw[k2] = u;
    }

    _Float16* __restrict__ rowbase = pre + (size_t)b * Tn * RS;
    const int poff = mv ? Hn : 0;    // pre-activation offset for this matvec
    float hprev = 0.0f;              // live in mv=0 threads

    // prologue: h0 = 0; prefetch pre rows 0..7 (own matvec's half)
    if (tid < Hn) hbuf[0][tid] = (_Float16)0.0f;
    float pc[8];
    #pragma unroll
    for (int k = 0; k < 8; ++k)
        pc[k] = (float)rowbase[(size_t)k * RS + poff + col];
    __syncthreads();

    for (int t0 = 0; t0 < Tn; t0 += 8) {
        // ---- batched prefetch of rows t0+8 .. t0+15 ----
        float pn[8];
        #pragma unroll
        for (int k = 0; k < 8; ++k) {
            int tn = t0 + 8 + k;
            if (tn > Tn - 1) tn = Tn - 1;
            pn[k] = (float)rowbase[(size_t)tn * RS + poff + col];
        }

        float hst[8];   // chunk store batch (mv=0 threads)

        #pragma unroll
        for (int ph = 0; ph < 8; ++ph) {
            const int t = t0 + ph;

            const f16x8* __restrict__ hb =
                reinterpret_cast<const f16x8*>(&hbuf[t & 1][0]);

            float acc[4] = {0.0f, 0.0f, 0.0f, 0.0f};

            // 32 broadcast b128 reads; 4 h2-pairs each; 4 indep dot chains
            #pragma unroll
            for (int r = 0; r < 32; ++r) {
                const f16x8 v = hb[r];                       // h[8r .. 8r+7]
                const h2 p0 = __builtin_shufflevector(v, v, 0, 1);
                const h2 p1 = __builtin_shufflevector(v, v, 2, 3);
                const h2 p2 = __builtin_shufflevector(v, v, 4, 5);
                const h2 p3 = __builtin_shufflevector(v, v, 6, 7);
                acc[0] = dot2(p0, bw[4 * r + 0], acc[0]);
                acc[1] = dot2(p1, bw[4 * r + 1], acc[1]);
                acc[2] = dot2(p2, bw[4 * r + 2], acc[2]);
                acc[3] = dot2(p3, bw[4 * r + 3], acc[3]);
            }
            const float y = (acc[0] + acc[1]) + (acc[2] + acc[3]) + pc[ph];

            // pre-barrier nonlinearity (off the critical path)
            float cand = 0.0f;
            if (mv) {
                abuf[col] = fast_sigmoid(y);   // publish alpha
            } else {
                cand = fast_tanh(y);
            }
            __syncthreads();   // alpha ready; all hbuf[t&1] reads done

            if (!mv) {
                const float alpha = abuf[col];
                const float hn = hprev + alpha * (cand - hprev);
                hprev = hn;
                hst[ph] = hn;
                hbuf[(t + 1) & 1][col] = (_Float16)hn;
            }
            __syncthreads();   // hbuf[(t+1)&1] ready; abuf reads done
        }

        // ---- chunk flush: batched global stores + rotate prefetch regs ----
        if (!mv) {
            if (writeF32) {
                #pragma unroll
                for (int k = 0; k < 8; ++k)
                    outf[((size_t)b * Tn + (t0 + k)) * Hn + col] = hst[k];
            } else {
                #pragma unroll
                for (int k = 0; k < 8; ++k)
                    rowbase[(size_t)(t0 + k) * RS + col] = (_Float16)hst[k];
            }
        }
        #pragma unroll
        for (int k = 0; k < 8; ++k) pc[k] = pn[k];
    }

    if (!mv) hfin[b * Hn + col] = hprev;
}

extern "C" void kernel_launch(void* const* d_in, const int* in_sizes, int n_in,
                              void* d_out, int out_size, void* d_ws, size_t ws_size,
                              hipStream_t stream) {
    const float* X    = (const float*)d_in[0];
    const float* Wih0 = (const float*)d_in[1];
    const float* Whh0 = (const float*)d_in[2];
    const float* bh0  = (const float*)d_in[3];
    const float* Wax0 = (const float*)d_in[4];
    const float* Wah0 = (const float*)d_in[5];
    const float* ba0  = (const float*)d_in[6];
    const float* Wih1 = (const float*)d_in[7];
    const float* Whh1 = (const float*)d_in[8];
    const float* bh1  = (const float*)d_in[9];
    const float* Wax1 = (const float*)d_in[10];
    const float* Wah1 = (const float*)d_in[11];
    const float* ba1  = (const float*)d_in[12];

    float* outf = (float*)d_out;
    float* hfin = outf + (size_t)Bn * Tn * Hn;
    _Float16* pre = (_Float16*)d_out;

    gemm_x_kernel<<<dim3((Bn * Tn) / 64, 2), 256, 0, stream>>>(X, Wih0, bh0, Wax0, ba0, pre);
    scan_dot2_kernel<<<dim3(Bn), 512, 0, stream>>>(pre, Whh0, Wah0, outf, hfin, 0);
    gemm_h_kernel<<<dim3((Bn * Tn) / 32), 256, 0, stream>>>(pre, Wih1, bh1, Wax1, ba1);
    scan_dot2_kernel<<<dim3(Bn), 512, 0, stream>>>(pre, Whh1, Wah1, outf, hfin + Bn * Hn, 1);
}